// Round 2
// baseline (875.632 us; speedup 1.0000x reference)
//
#include <hip/hip_runtime.h>
#include <stdint.h>

#define HIDDEN  2560
#define NHEADS  32
#define HEAD    80
#define DSTRIDE 128          // Q/K padded head stride (multiple of 32 for MFMA K)
#define SEQ     2048
#define BATCH   2
#define M_TOTAL (BATCH*SEQ)  // 4096
#define QKV_N   (3*HIDDEN)   // 7680

typedef __attribute__((ext_vector_type(8))) short  short8;
typedef __attribute__((ext_vector_type(4))) float  floatx4;
typedef __attribute__((ext_vector_type(4))) float  fvec4;
typedef __attribute__((ext_vector_type(4))) unsigned short usvec4;

__device__ __forceinline__ unsigned short f2bf(float x){
  union { float f; unsigned u; } v; v.f = x;
  unsigned r = v.u + 0x7fffu + ((v.u >> 16) & 1u);
  return (unsigned short)(r >> 16);
}
__device__ __forceinline__ float bf2f(unsigned short h){
  union { unsigned u; float f; } v; v.u = ((unsigned)h) << 16;
  return v.f;
}

__device__ __forceinline__ void gload16(const void* g, void* l){
  __builtin_amdgcn_global_load_lds(
    (const __attribute__((address_space(1))) void*)g,
    (__attribute__((address_space(3))) void*)l, 16, 0, 0);
}

// ---------------- f32 -> bf16 convert ----------------
__global__ __launch_bounds__(256)
void convert_f32_bf16(const float* __restrict__ src, unsigned short* __restrict__ dst, int n4){
  int idx = blockIdx.x*blockDim.x + threadIdx.x;
  int stride = gridDim.x*blockDim.x;
  for (int i = idx; i < n4; i += stride){
    fvec4 v = *(const fvec4*)(src + (size_t)i*4);
    usvec4 o;
    o[0]=f2bf(v[0]); o[1]=f2bf(v[1]); o[2]=f2bf(v[2]); o[3]=f2bf(v[3]);
    *(usvec4*)(dst + (size_t)i*4) = o;
  }
}

// ---------------- GEMM: C[M,N] = A[M,K] * B[N,K]^T + bias ----------------
// 128x128 tile, BK=64, 4 waves (each 64x64), global_load_lds staging,
// XOR-swizzled LDS, XCD-aware tile swizzle (grid must be %8==0).
template<bool OUT_BF16>
__global__ __launch_bounds__(256)
void gemm_bt(const unsigned short* __restrict__ A, const unsigned short* __restrict__ Bm,
             const float* __restrict__ bias, void* __restrict__ Cout,
             int M, int N, int K)
{
  __shared__ __align__(16) unsigned short Alds[128*64];
  __shared__ __align__(16) unsigned short Blds[128*64];
  const int tid  = threadIdx.x;
  const int lane = tid & 63;
  const int wid  = tid >> 6;
  const int wr   = wid >> 1, wc = wid & 1;

  // XCD-aware swizzle: blocks on one XCD (lid%8) get a contiguous tile range
  const int gx  = gridDim.x;
  const int lid = blockIdx.y*gx + blockIdx.x;
  const int nwg = gx*gridDim.y;
  const int qch = nwg >> 3;
  const int sl  = (lid & 7)*qch + (lid >> 3);
  const int bx  = sl % gx, by = sl / gx;

  const int rowA0 = by * 128;
  const int rowB0 = bx * 128;
  const int l15 = lane & 15, lg = lane >> 4;

  floatx4 acc[4][4];
  #pragma unroll
  for (int i=0;i<4;i++)
    #pragma unroll
    for (int j=0;j<4;j++) acc[i][j] = (floatx4)0.0f;

  int srow[4], scol[4];
  #pragma unroll
  for (int i=0;i<4;i++){
    int c = wid*4 + i;
    int e = c*512 + lane*8;
    int row = e >> 6;            // 64 elems per row
    int col8 = (e >> 3) & 7;     // 16B chunk within row
    srow[i] = row;
    scol[i] = ((col8 ^ (row & 7)) << 3);  // pre-swizzled source column
  }

  for (int k0 = 0; k0 < K; k0 += 64){
    #pragma unroll
    for (int i=0;i<4;i++){
      int c = wid*4 + i;
      gload16(A  + (size_t)(rowA0 + srow[i])*K + k0 + scol[i], &Alds[c*512]);
      gload16(Bm + (size_t)(rowB0 + srow[i])*K + k0 + scol[i], &Blds[c*512]);
    }
    __syncthreads();
    #pragma unroll
    for (int kk = 0; kk < 64; kk += 32){
      short8 af[4], bfv[4];
      #pragma unroll
      for (int mi=0; mi<4; mi++){
        int r = wr*64 + mi*16 + l15;
        int ch = ((kk>>3) + lg) ^ (r & 7);
        af[mi] = *(const short8*)&Alds[r*64 + ch*8];
      }
      #pragma unroll
      for (int ni=0; ni<4; ni++){
        int r = wc*64 + ni*16 + l15;
        int ch = ((kk>>3) + lg) ^ (r & 7);
        bfv[ni] = *(const short8*)&Blds[r*64 + ch*8];
      }
      #pragma unroll
      for (int mi=0; mi<4; mi++)
        #pragma unroll
        for (int ni=0; ni<4; ni++)
          acc[mi][ni] = __builtin_amdgcn_mfma_f32_16x16x32_bf16(af[mi], bfv[ni], acc[mi][ni], 0, 0, 0);
    }
    __syncthreads();
  }

  #pragma unroll
  for (int mi=0; mi<4; mi++){
    #pragma unroll
    for (int ni=0; ni<4; ni++){
      int col = rowB0 + wc*64 + ni*16 + l15;
      float bs = bias[col];
      #pragma unroll
      for (int r=0;r<4;r++){
        int row = rowA0 + wr*64 + mi*16 + lg*4 + r;
        float v = acc[mi][ni][r] + bs;
        if (OUT_BF16) ((unsigned short*)Cout)[(size_t)row*N + col] = f2bf(v);
        else          ((float*)Cout)[(size_t)row*N + col] = v;
      }
    }
  }
}

// ---------------- RoPE + scatter to attention layouts ----------------
__global__ __launch_bounds__(256)
void rope_scatter(const unsigned short* __restrict__ qkv,
                  const int* __restrict__ pos_ids,
                  unsigned short* __restrict__ Qp, unsigned short* __restrict__ Kp,
                  unsigned short* __restrict__ Vt)
{
  __shared__ float cosb[128*16];
  __shared__ float sinb[128*16];
  __shared__ __align__(16) unsigned short vtile[128*88];
  const int tid = threadIdx.x;
  const int blk = blockIdx.x;
  const int st = blk & 15, h = (blk >> 4) & 31, b = blk >> 9;
  const int s0 = st*128;

  for (int idx = tid; idx < 128*16; idx += 256){
    int sl = idx >> 4, i = idx & 15;
    float p = (float)pos_ids[b*SEQ + s0 + sl];
    float inv = exp2f(-(float)i * (13.287712379549449f/16.0f));
    float ang = p * inv;
    cosb[idx] = cosf(ang);
    sinb[idx] = sinf(ang);
  }
  __syncthreads();

  const size_t qkrow = (size_t)(b*SEQ + s0)*QKV_N;
  const size_t obase = ((size_t)(b*NHEADS + h)*SEQ + s0)*DSTRIDE;
  #pragma unroll
  for (int part = 0; part < 2; part++){
    const int cbase = part*HIDDEN + h*HEAD;
    unsigned short* outp = part ? Kp : Qp;
    for (int idx = tid; idx < 128*DSTRIDE; idx += 256){
      int sl = idx >> 7, d = idx & 127;
      const size_t rb = qkrow + (size_t)sl*QKV_N + cbase;
      float v;
      if (d < 16){
        float x1 = bf2f(qkv[rb + d]);
        float x2 = bf2f(qkv[rb + d + 16]);
        v = x1*cosb[sl*16 + d] - x2*sinb[sl*16 + d];
      } else if (d < 32){
        int i = d - 16;
        float x1 = bf2f(qkv[rb + d - 16]);
        float x2 = bf2f(qkv[rb + d]);
        v = x2*cosb[sl*16 + i] + x1*sinb[sl*16 + i];
      } else if (d < HEAD){
        v = bf2f(qkv[rb + d]);
      } else v = 0.0f;
      outp[obase + (size_t)sl*DSTRIDE + d] = f2bf(v);
    }
  }

  for (int idx = tid; idx < 128*HEAD; idx += 256){
    int sl = idx / HEAD, d = idx - sl*HEAD;
    vtile[sl*88 + d] = qkv[qkrow + (size_t)sl*QKV_N + 2*HIDDEN + h*HEAD + d];
  }
  __syncthreads();
  const size_t vtb = ((size_t)(b*NHEADS + h)*HEAD)*SEQ + s0;
  for (int idx = tid; idx < HEAD*128; idx += 256){
    int d = idx >> 7, sl = idx & 127;
    Vt[vtb + (size_t)d*SEQ + sl] = vtile[sl*88 + d];
  }
}

// ---------------- flash attention (causal) ----------------
// 1D grid 1024: XCD-grouped (b,h), heavy q-tiles first.
// Block: 4 waves x 32 q-rows = 128 rows. K/V tiles LDS-staged, shared by waves.
__global__ __launch_bounds__(256)
void attn_kernel(const unsigned short* __restrict__ Qp,
                 const unsigned short* __restrict__ Kp,
                 const unsigned short* __restrict__ Vt,
                 unsigned short* __restrict__ ctx)
{
  __shared__ __align__(16) unsigned short Klds[64*128];   // 16 KB, swizzled
  __shared__ __align__(16) unsigned short Vlds[80*64];    // 10 KB, swizzled
  __shared__ __align__(16) unsigned short p_lds[4][32*72];

  const int tid = threadIdx.x;
  const int lane = tid & 63, w = tid >> 6;
  const int l15 = lane & 15, lg = lane >> 4;

  const int bid = blockIdx.x;            // 0..1023
  const int xcd = bid & 7, j = bid >> 3; // j: 0..127
  const int bh  = xcd + 8*(j >> 4);      // all 16 q-tiles of a head on one XCD
  const int qt  = 15 - (j & 15);         // heavy tiles dispatched first
  const int b   = bh >> 5, h = bh & 31;

  const int q0 = qt*128 + w*32;
  const unsigned short* Qbase = Qp + ((size_t)bh*SEQ)*DSTRIDE;
  const unsigned short* Kbase = Kp + ((size_t)bh*SEQ)*DSTRIDE;
  const unsigned short* Vbase = Vt + ((size_t)bh*HEAD)*SEQ;

  // Q fragments in registers: rows q0..q0+31, D cols 0..95
  short8 qf[2][3];
  #pragma unroll
  for (int mi=0; mi<2; mi++)
    #pragma unroll
    for (int kc=0; kc<3; kc++)
      qf[mi][kc] = *(const short8*)&Qbase[(size_t)(q0 + mi*16 + l15)*DSTRIDE + kc*32 + lg*8];

  float mrun[2][4], lrun[2][4];
  floatx4 oacc[2][5];
  #pragma unroll
  for (int mi=0;mi<2;mi++){
    #pragma unroll
    for (int r=0;r<4;r++){ mrun[mi][r] = -1e30f; lrun[mi][r] = 0.0f; }
    #pragma unroll
    for (int di=0;di<5;di++) oacc[mi][di] = (floatx4)0.0f;
  }

  const float SC = 0.1118033988749895f * 1.4426950408889634f; // 1/sqrt(80)*log2(e)
  const int nkt_w = ((q0 + 31) >> 6) + 1;  // wave's causal tile count
  const int nkt_b = 2*qt + 2;              // block's tile count

  // staging geometry (pre-swizzled global source, linear LDS dest)
  int krow[4], kcol[4];
  #pragma unroll
  for (int i=0;i<4;i++){
    int r = (w*4+i)*4 + lg;
    krow[i] = r;
    kcol[i] = (l15 ^ (r & 7)) << 3;
  }
  int vrow[3], vcol[3];
  #pragma unroll
  for (int t=0;t<3;t++){
    int i = w + 4*t;
    int r = i*8 + (lane >> 3);
    vrow[t] = r;
    vcol[t] = ((lane & 7) ^ (r & 7)) << 3;
  }

  for (int kt = 0; kt < nkt_b; kt++){
    // ---- stage K (4 issues/wave) and V (10 issues total) ----
    #pragma unroll
    for (int i=0;i<4;i++)
      gload16(Kbase + (size_t)(kt*64 + krow[i])*DSTRIDE + kcol[i], &Klds[(w*4+i)*512]);
    #pragma unroll
    for (int t=0;t<3;t++){
      int i = w + 4*t;
      if (i < 10)
        gload16(Vbase + (size_t)vrow[t]*SEQ + kt*64 + vcol[t], &Vlds[i*512]);
    }
    __syncthreads();   // drains vmcnt: tile ready

    if (kt < nkt_w){
      floatx4 sacc[2][4];
      #pragma unroll
      for (int mi=0;mi<2;mi++)
        #pragma unroll
        for (int ni=0;ni<4;ni++) sacc[mi][ni] = (floatx4)0.0f;

      // S = Q K^T from swizzled LDS
      __builtin_amdgcn_s_setprio(1);
      #pragma unroll
      for (int kc=0; kc<3; kc++){
        short8 kf[4];
        #pragma unroll
        for (int ni=0; ni<4; ni++){
          int r = ni*16 + l15;
          int ch = (kc*4 + lg) ^ (r & 7);
          kf[ni] = *(const short8*)&Klds[r*128 + ch*8];
        }
        #pragma unroll
        for (int mi=0; mi<2; mi++)
          #pragma unroll
          for (int ni=0; ni<4; ni++)
            sacc[mi][ni] = __builtin_amdgcn_mfma_f32_16x16x32_bf16(qf[mi][kc], kf[ni], sacc[mi][ni], 0, 0, 0);
      }
      __builtin_amdgcn_s_setprio(0);

      // causal mask only on diagonal tiles (wave-uniform branch)
      if (kt*64 + 63 > q0){
        #pragma unroll
        for (int mi=0; mi<2; mi++)
          #pragma unroll
          for (int ni=0; ni<4; ni++)
            #pragma unroll
            for (int r=0; r<4; r++){
              int qg = q0 + mi*16 + lg*4 + r;
              int kg = kt*64 + ni*16 + l15;
              if (kg > qg) sacc[mi][ni][r] = -1e30f;
            }
      }

      // row max (raw domain) + rescale-skip detection
      float pmv[2][4];
      float need = 0.0f;
      #pragma unroll
      for (int mi=0; mi<2; mi++)
        #pragma unroll
        for (int r=0; r<4; r++){
          float pm = fmaxf(fmaxf(sacc[mi][0][r], sacc[mi][1][r]),
                           fmaxf(sacc[mi][2][r], sacc[mi][3][r]));
          pm = fmaxf(pm, __shfl_xor(pm, 1));
          pm = fmaxf(pm, __shfl_xor(pm, 2));
          pm = fmaxf(pm, __shfl_xor(pm, 4));
          pm = fmaxf(pm, __shfl_xor(pm, 8));
          pmv[mi][r] = pm;
          need = fmaxf(need, pm - mrun[mi][r]);
        }
      const bool full = __any(need > 0.0f);  // wave-uniform: rescale needed?

      #pragma unroll
      for (int mi=0; mi<2; mi++)
        #pragma unroll
        for (int r=0; r<4; r++){
          float mold = mrun[mi][r];
          float mnew = full ? fmaxf(mold, pmv[mi][r]) : mold;
          float rs = 0.0f;
          #pragma unroll
          for (int ni=0; ni<4; ni++){
            float p = exp2f((sacc[mi][ni][r] - mnew) * SC);
            sacc[mi][ni][r] = p;
            rs += p;
          }
          rs += __shfl_xor(rs, 1);
          rs += __shfl_xor(rs, 2);
          rs += __shfl_xor(rs, 4);
          rs += __shfl_xor(rs, 8);
          if (full){
            float alpha = exp2f((mold - mnew) * SC);
            lrun[mi][r] = lrun[mi][r]*alpha + rs;
            mrun[mi][r] = mnew;
            #pragma unroll
            for (int di=0; di<5; di++) oacc[mi][di][r] *= alpha;
          } else {
            lrun[mi][r] += rs;
          }
        }

      // P -> LDS (per-wave region)
      #pragma unroll
      for (int mi=0; mi<2; mi++)
        #pragma unroll
        for (int ni=0; ni<4; ni++)
          #pragma unroll
          for (int r=0; r<4; r++){
            int row = mi*16 + lg*4 + r;
            p_lds[w][row*72 + ni*16 + l15] = f2bf(sacc[mi][ni][r]);
          }

      // O += P V  (V from swizzled LDS)
      __builtin_amdgcn_s_setprio(1);
      #pragma unroll
      for (int kk=0; kk<2; kk++){
        short8 pa[2];
        #pragma unroll
        for (int mi=0;mi<2;mi++)
          pa[mi] = *(const short8*)&p_lds[w][(mi*16 + l15)*72 + kk*32 + lg*8];
        #pragma unroll
        for (int di=0; di<5; di++){
          int r = di*16 + l15;
          int ch = (kk*4 + lg) ^ (r & 7);
          short8 vf = *(const short8*)&Vlds[r*64 + ch*8];
          #pragma unroll
          for (int mi=0;mi<2;mi++)
            oacc[mi][di] = __builtin_amdgcn_mfma_f32_16x16x32_bf16(pa[mi], vf, oacc[mi][di], 0, 0, 0);
        }
      }
      __builtin_amdgcn_s_setprio(0);
    }
    __syncthreads();   // all waves done with LDS tile before restage
  }

  #pragma unroll
  for (int mi=0;mi<2;mi++)
    #pragma unroll
    for (int di=0;di<5;di++)
      #pragma unroll
      for (int r=0;r<4;r++){
        int q = q0 + mi*16 + lg*4 + r;
        float v = oacc[mi][di][r] / lrun[mi][r];
        ctx[((size_t)(b*SEQ + q))*HIDDEN + h*HEAD + di*16 + l15] = f2bf(v);
      }
}

// ---------------- launch ----------------
extern "C" void kernel_launch(void* const* d_in, const int* in_sizes, int n_in,
                              void* d_out, int out_size, void* d_ws, size_t ws_size,
                              hipStream_t stream)
{
  const int*   pos  = (const int*)  d_in[0];
  const float* hid  = (const float*)d_in[1];
  const float* wqkv = (const float*)d_in[2];
  const float* bqkv = (const float*)d_in[3];
  const float* outw = (const float*)d_in[4];
  const float* outb = (const float*)d_in[5];

  char* ws = (char*)d_ws;
  size_t off = 0;
  auto alloc = [&](size_t bytes)->void*{
    void* p = ws + off; off += (bytes + 255) & ~(size_t)255; return p;
  };
  unsigned short* hid_bf  = (unsigned short*)alloc((size_t)M_TOTAL*HIDDEN*2);   // reused as ctx
  unsigned short* wqkv_bf = (unsigned short*)alloc((size_t)QKV_N*HIDDEN*2);
  unsigned short* outw_bf = (unsigned short*)alloc((size_t)HIDDEN*HIDDEN*2);
  unsigned short* qkv_bf  = (unsigned short*)alloc((size_t)M_TOTAL*QKV_N*2);
  unsigned short* Qp      = (unsigned short*)alloc((size_t)BATCH*NHEADS*SEQ*DSTRIDE*2);
  unsigned short* Kp      = (unsigned short*)alloc((size_t)BATCH*NHEADS*SEQ*DSTRIDE*2);
  unsigned short* Vt      = (unsigned short*)alloc((size_t)BATCH*NHEADS*HEAD*SEQ*2);
  if (off > ws_size) return;

  convert_f32_bf16<<<dim3(1024), dim3(256), 0, stream>>>(hid,  hid_bf,  M_TOTAL*HIDDEN/4);
  convert_f32_bf16<<<dim3(2048), dim3(256), 0, stream>>>(wqkv, wqkv_bf, QKV_N*HIDDEN/4);
  convert_f32_bf16<<<dim3(1024), dim3(256), 0, stream>>>(outw, outw_bf, HIDDEN*HIDDEN/4);

  gemm_bt<true><<<dim3(QKV_N/128, M_TOTAL/128), dim3(256), 0, stream>>>(
      hid_bf, wqkv_bf, bqkv, (void*)qkv_bf, M_TOTAL, QKV_N, HIDDEN);

  rope_scatter<<<dim3(BATCH*NHEADS*16), dim3(256), 0, stream>>>(qkv_bf, pos, Qp, Kp, Vt);

  unsigned short* ctx = hid_bf;  // hidden_bf dead after QKV GEMM
  attn_kernel<<<dim3(1024), dim3(256), 0, stream>>>(Qp, Kp, Vt, ctx);

  gemm_bt<false><<<dim3(HIDDEN/128, M_TOTAL/128), dim3(256), 0, stream>>>(
      ctx, outw_bf, outb, d_out, M_TOTAL, HIDDEN, HIDDEN);
}

// Round 7
// 804.429 us; speedup vs baseline: 1.0885x; 1.0885x over previous
//
#include <hip/hip_runtime.h>
#include <stdint.h>

#define HIDDEN  2560
#define NHEADS  32
#define HEAD    80
#define DSTRIDE 128          // Q/K padded head stride (multiple of 32 for MFMA K)
#define SEQ     2048
#define BATCH   2
#define M_TOTAL (BATCH*SEQ)  // 4096
#define QKV_N   (3*HIDDEN)   // 7680

typedef __attribute__((ext_vector_type(8))) short  short8;
typedef __attribute__((ext_vector_type(4))) float  floatx4;
typedef __attribute__((ext_vector_type(4))) float  fvec4;
typedef __attribute__((ext_vector_type(4))) unsigned short usvec4;
typedef __attribute__((ext_vector_type(2))) unsigned int uint2v;

__device__ __forceinline__ unsigned short f2bf(float x){
  union { float f; unsigned u; } v; v.f = x;
  unsigned r = v.u + 0x7fffu + ((v.u >> 16) & 1u);
  return (unsigned short)(r >> 16);
}
__device__ __forceinline__ float bf2f(unsigned short h){
  union { unsigned u; float f; } v; v.u = ((unsigned)h) << 16;
  return v.f;
}
__device__ __forceinline__ unsigned cvt_pk_bf16(float lo, float hi){
  unsigned r;
  asm volatile("v_cvt_pk_bf16_f32 %0, %1, %2" : "=v"(r) : "v"(lo), "v"(hi));
  return r;
}

__device__ __forceinline__ void gload16(const void* g, void* l){
  __builtin_amdgcn_global_load_lds(
    (const __attribute__((address_space(1))) void*)g,
    (__attribute__((address_space(3))) void*)l, 16, 0, 0);
}

// ---------------- f32 -> bf16 convert ----------------
__global__ __launch_bounds__(256)
void convert_f32_bf16(const float* __restrict__ src, unsigned short* __restrict__ dst, int n4){
  int idx = blockIdx.x*blockDim.x + threadIdx.x;
  int stride = gridDim.x*blockDim.x;
  for (int i = idx; i < n4; i += stride){
    fvec4 v = *(const fvec4*)(src + (size_t)i*4);
    usvec4 o;
    o[0]=f2bf(v[0]); o[1]=f2bf(v[1]); o[2]=f2bf(v[2]); o[3]=f2bf(v[3]);
    *(usvec4*)(dst + (size_t)i*4) = o;
  }
}

// ---------------- GEMM: C[M,N] = A[M,K] * B[N,K]^T + bias ----------------
template<bool OUT_BF16>
__global__ __launch_bounds__(256)
void gemm_bt(const unsigned short* __restrict__ A, const unsigned short* __restrict__ Bm,
             const float* __restrict__ bias, void* __restrict__ Cout,
             int M, int N, int K)
{
  __shared__ __align__(16) unsigned short Alds[128*64];
  __shared__ __align__(16) unsigned short Blds[128*64];
  const int tid  = threadIdx.x;
  const int lane = tid & 63;
  const int wid  = tid >> 6;
  const int wr   = wid >> 1, wc = wid & 1;

  const int gx  = gridDim.x;
  const int lid = blockIdx.y*gx + blockIdx.x;
  const int nwg = gx*gridDim.y;
  const int qch = nwg >> 3;
  const int sl  = (lid & 7)*qch + (lid >> 3);
  const int bx  = sl % gx, by = sl / gx;

  const int rowA0 = by * 128;
  const int rowB0 = bx * 128;
  const int l15 = lane & 15, lg = lane >> 4;

  floatx4 acc[4][4];
  #pragma unroll
  for (int i=0;i<4;i++)
    #pragma unroll
    for (int j=0;j<4;j++) acc[i][j] = (floatx4)0.0f;

  int srow[4], scol[4];
  #pragma unroll
  for (int i=0;i<4;i++){
    int c = wid*4 + i;
    int e = c*512 + lane*8;
    int row = e >> 6;
    int col8 = (e >> 3) & 7;
    srow[i] = row;
    scol[i] = ((col8 ^ (row & 7)) << 3);
  }

  for (int k0 = 0; k0 < K; k0 += 64){
    #pragma unroll
    for (int i=0;i<4;i++){
      int c = wid*4 + i;
      gload16(A  + (size_t)(rowA0 + srow[i])*K + k0 + scol[i], &Alds[c*512]);
      gload16(Bm + (size_t)(rowB0 + srow[i])*K + k0 + scol[i], &Blds[c*512]);
    }
    __syncthreads();
    #pragma unroll
    for (int kk = 0; kk < 64; kk += 32){
      short8 af[4], bfv[4];
      #pragma unroll
      for (int mi=0; mi<4; mi++){
        int r = wr*64 + mi*16 + l15;
        int ch = ((kk>>3) + lg) ^ (r & 7);
        af[mi] = *(const short8*)&Alds[r*64 + ch*8];
      }
      #pragma unroll
      for (int ni=0; ni<4; ni++){
        int r = wc*64 + ni*16 + l15;
        int ch = ((kk>>3) + lg) ^ (r & 7);
        bfv[ni] = *(const short8*)&Blds[r*64 + ch*8];
      }
      #pragma unroll
      for (int mi=0; mi<4; mi++)
        #pragma unroll
        for (int ni=0; ni<4; ni++)
          acc[mi][ni] = __builtin_amdgcn_mfma_f32_16x16x32_bf16(af[mi], bfv[ni], acc[mi][ni], 0, 0, 0);
    }
    __syncthreads();
  }

  #pragma unroll
  for (int mi=0; mi<4; mi++){
    #pragma unroll
    for (int ni=0; ni<4; ni++){
      int col = rowB0 + wc*64 + ni*16 + l15;
      float bs = bias[col];
      #pragma unroll
      for (int r=0;r<4;r++){
        int row = rowA0 + wr*64 + mi*16 + lg*4 + r;
        float v = acc[mi][ni][r] + bs;
        if (OUT_BF16) ((unsigned short*)Cout)[(size_t)row*N + col] = f2bf(v);
        else          ((float*)Cout)[(size_t)row*N + col] = v;
      }
    }
  }
}

// ---------------- RoPE + scatter to attention layouts ----------------
__global__ __launch_bounds__(256)
void rope_scatter(const unsigned short* __restrict__ qkv,
                  const int* __restrict__ pos_ids,
                  unsigned short* __restrict__ Qp, unsigned short* __restrict__ Kp,
                  unsigned short* __restrict__ Vt)
{
  __shared__ float cosb[128*16];
  __shared__ float sinb[128*16];
  __shared__ __align__(16) unsigned short vtile[128*88];
  const int tid = threadIdx.x;
  const int blk = blockIdx.x;
  const int st = blk & 15, h = (blk >> 4) & 31, b = blk >> 9;
  const int s0 = st*128;

  for (int idx = tid; idx < 128*16; idx += 256){
    int sl = idx >> 4, i = idx & 15;
    float p = (float)pos_ids[b*SEQ + s0 + sl];
    float inv = exp2f(-(float)i * (13.287712379549449f/16.0f));
    float ang = p * inv;
    cosb[idx] = cosf(ang);
    sinb[idx] = sinf(ang);
  }
  __syncthreads();

  const size_t qkrow = (size_t)(b*SEQ + s0)*QKV_N;
  const size_t obase = ((size_t)(b*NHEADS + h)*SEQ + s0)*DSTRIDE;
  #pragma unroll
  for (int part = 0; part < 2; part++){
    const int cbase = part*HIDDEN + h*HEAD;
    unsigned short* outp = part ? Kp : Qp;
    for (int idx = tid; idx < 128*DSTRIDE; idx += 256){
      int sl = idx >> 7, d = idx & 127;
      const size_t rb = qkrow + (size_t)sl*QKV_N + cbase;
      float v;
      if (d < 16){
        float x1 = bf2f(qkv[rb + d]);
        float x2 = bf2f(qkv[rb + d + 16]);
        v = x1*cosb[sl*16 + d] - x2*sinb[sl*16 + d];
      } else if (d < 32){
        int i = d - 16;
        float x1 = bf2f(qkv[rb + d - 16]);
        float x2 = bf2f(qkv[rb + d]);
        v = x2*cosb[sl*16 + i] + x1*sinb[sl*16 + i];
      } else if (d < HEAD){
        v = bf2f(qkv[rb + d]);
      } else v = 0.0f;
      outp[obase + (size_t)sl*DSTRIDE + d] = f2bf(v);
    }
  }

  for (int idx = tid; idx < 128*HEAD; idx += 256){
    int sl = idx / HEAD, d = idx - sl*HEAD;
    vtile[sl*88 + d] = qkv[qkrow + (size_t)sl*QKV_N + 2*HIDDEN + h*HEAD + d];
  }
  __syncthreads();
  const size_t vtb = ((size_t)(b*NHEADS + h)*HEAD)*SEQ + s0;
  for (int idx = tid; idx < HEAD*128; idx += 256){
    int d = idx >> 7, sl = idx & 127;
    Vt[vtb + (size_t)d*SEQ + sl] = vtile[sl*88 + d];
  }
}

// ---------------- flash-decode attention (causal, swapped-operand MFMA) ----
// wave-task = (bh, 32-row q-chunk, kv-part of <=8 key-tiles). 160 tasks/bh.
// 2560 blocks x 4 waves. Multi-part tasks emit unnormalized partials.
#define PART_SLOTS 144
__global__ __launch_bounds__(256, 4)
void attn_fd(const unsigned short* __restrict__ Qp,
             const unsigned short* __restrict__ Kp,
             const unsigned short* __restrict__ Vt,
             unsigned short* __restrict__ ctx,
             unsigned short* __restrict__ pO,
             float* __restrict__ pML)
{
  __shared__ __align__(16) unsigned short p_lds[4][32*72];
  const int tid = threadIdx.x;
  const int lane = tid & 63, w = tid >> 6;
  const int l15 = lane & 15, lg = lane >> 4;

  // task decode: bid 0..2559 -> xcd-grouped bh, task index tr 0..159
  const int bid = blockIdx.x;
  const int xcd = bid & 7, j = bid >> 3;          // j 0..319
  const int bh  = (j/40)*8 + xcd;                  // 0..63
  const int tr  = (j - (j/40)*40)*4 + w;           // 0..159

  int qc, part, np;
  if (tr < 16){ qc = tr; part = 0; np = 1; }
  else if (tr < 48){ int t = tr-16; qc = 16 + (t>>1); part = t&1; np = 2; }
  else if (tr < 96){ int t = tr-48; int q3 = t/3; qc = 32 + q3; part = t - q3*3; np = 3; }
  else { int t = tr-96; qc = 48 + (t>>2); part = t&3; np = 4; }
  const int nkt = (qc >> 1) + 1;
  const int kt0 = (part*nkt)/np, kt1 = ((part+1)*nkt)/np;
  const int q0  = qc*32;

  const unsigned short* Qb = Qp + ((size_t)bh*SEQ)*DSTRIDE;
  const unsigned short* Kb = Kp + ((size_t)bh*SEQ)*DSTRIDE;
  const unsigned short* Vb = Vt + ((size_t)bh*HEAD)*SEQ;

  // Q fragments: rows q0..q0+31, D cols 0..95 (96..127 are zeros)
  short8 qf[2][3];
  #pragma unroll
  for (int mi=0; mi<2; mi++)
    #pragma unroll
    for (int kc=0; kc<3; kc++)
      qf[mi][kc] = *(const short8*)&Qb[(size_t)(q0 + mi*16 + l15)*DSTRIDE + kc*32 + lg*8];

  float mrun[2] = {-3e38f, -3e38f};
  float lrun[2] = {0.0f, 0.0f};
  floatx4 oacc[2][5];
  #pragma unroll
  for (int mi=0;mi<2;mi++)
    #pragma unroll
    for (int di=0;di<5;di++) oacc[mi][di] = (floatx4)0.0f;

  const float SC = 0.1118033988749895f * 1.4426950408889634f; // 1/sqrt(80)*log2(e)

  for (int kt = kt0; kt < kt1; kt++){
    floatx4 sacc[2][4];
    #pragma unroll
    for (int mi=0;mi<2;mi++)
      #pragma unroll
      for (int ni=0;ni<4;ni++) sacc[mi][ni] = (floatx4)0.0f;

    // S^T = K Q^T : C[row=k-local(lg*4+r)][col=q-local(l15)]
    __builtin_amdgcn_s_setprio(1);
    #pragma unroll
    for (int kc=0; kc<3; kc++){
      short8 kf[4];
      #pragma unroll
      for (int ni=0; ni<4; ni++)
        kf[ni] = *(const short8*)&Kb[(size_t)(kt*64 + ni*16 + l15)*DSTRIDE + kc*32 + lg*8];
      #pragma unroll
      for (int mi=0; mi<2; mi++)
        #pragma unroll
        for (int ni=0; ni<4; ni++)
          sacc[mi][ni] = __builtin_amdgcn_mfma_f32_16x16x32_bf16(kf[ni], qf[mi][kc], sacc[mi][ni], 0, 0, 0);
    }
    __builtin_amdgcn_s_setprio(0);

    // causal mask (only the last tile of this q-chunk crosses the diagonal)
    if (kt == nkt-1){
      #pragma unroll
      for (int mi=0; mi<2; mi++){
        int qrow = q0 + mi*16 + l15;
        #pragma unroll
        for (int ni=0; ni<4; ni++){
          int kb = kt*64 + ni*16 + lg*4;
          #pragma unroll
          for (int r=0; r<4; r++)
            if (kb + r > qrow) sacc[mi][ni][r] = -3e38f;
        }
      }
    }

    // softmax: q-row is lane-local (16 scores in-register) + 2 shfl across lg
    #pragma unroll
    for (int mi=0; mi<2; mi++){
      float pm = -3e38f;
      #pragma unroll
      for (int ni=0; ni<4; ni++)
        #pragma unroll
        for (int r=0; r<4; r++) pm = fmaxf(pm, sacc[mi][ni][r]);
      pm = fmaxf(pm, __shfl_xor(pm, 16));
      pm = fmaxf(pm, __shfl_xor(pm, 32));
      float mold = mrun[mi];
      float mnew = fmaxf(mold, pm);
      float msc  = mnew*SC;
      float alpha = __builtin_amdgcn_exp2f(mold*SC - msc);
      float rs = 0.0f;
      #pragma unroll
      for (int ni=0; ni<4; ni++)
        #pragma unroll
        for (int r=0; r<4; r++){
          float p = __builtin_amdgcn_exp2f(sacc[mi][ni][r]*SC - msc);
          sacc[mi][ni][r] = p;
          rs += p;
        }
      rs += __shfl_xor(rs, 16);
      rs += __shfl_xor(rs, 32);
      lrun[mi] = lrun[mi]*alpha + rs;
      mrun[mi] = mnew;
      #pragma unroll
      for (int di=0; di<5; di++) oacc[mi][di] *= alpha;
    }

    // P pack -> LDS [q=32][k=64] stride 72 (per-wave region, b64 writes)
    #pragma unroll
    for (int mi=0; mi<2; mi++)
      #pragma unroll
      for (int ni=0; ni<4; ni++){
        uint2v pk;
        pk[0] = cvt_pk_bf16(sacc[mi][ni][0], sacc[mi][ni][1]);
        pk[1] = cvt_pk_bf16(sacc[mi][ni][2], sacc[mi][ni][3]);
        *(uint2v*)&p_lds[w][(mi*16 + l15)*72 + ni*16 + lg*4] = pk;
      }

    // O^T += V P^T : C[row=d-local][col=q-local] — q stays on l15, no redistrib
    __builtin_amdgcn_s_setprio(1);
    #pragma unroll
    for (int kk=0; kk<2; kk++){
      short8 pa[2];
      #pragma unroll
      for (int mi=0;mi<2;mi++)
        pa[mi] = *(const short8*)&p_lds[w][(mi*16 + l15)*72 + kk*32 + lg*8];
      #pragma unroll
      for (int di=0; di<5; di++){
        short8 vf = *(const short8*)&Vb[(size_t)(di*16 + l15)*SEQ + kt*64 + kk*32 + lg*8];
        #pragma unroll
        for (int mi=0;mi<2;mi++)
          oacc[mi][di] = __builtin_amdgcn_mfma_f32_16x16x32_bf16(vf, pa[mi], oacc[mi][di], 0, 0, 0);
      }
    }
    __builtin_amdgcn_s_setprio(0);
  }

  const int b = bh >> 5, h = bh & 31;
  if (np == 1){
    // final: normalize, write ctx (q = mi*16+l15, d = di*16+lg*4+r)
    #pragma unroll
    for (int mi=0;mi<2;mi++){
      float inv = 1.0f/lrun[mi];
      size_t crow = ((size_t)(b*SEQ + q0 + mi*16 + l15))*HIDDEN + h*HEAD;
      #pragma unroll
      for (int di=0;di<5;di++){
        uint2v pk;
        pk[0] = cvt_pk_bf16(oacc[mi][di][0]*inv, oacc[mi][di][1]*inv);
        pk[1] = cvt_pk_bf16(oacc[mi][di][2]*inv, oacc[mi][di][3]*inv);
        *(uint2v*)&ctx[crow + di*16 + lg*4] = pk;
      }
    }
  } else {
    const int pslot = bh*PART_SLOTS + (tr - 16);
    unsigned short* Ob = pO + (size_t)pslot*32*HEAD;
    #pragma unroll
    for (int mi=0;mi<2;mi++){
      #pragma unroll
      for (int di=0;di<5;di++){
        uint2v pk;
        pk[0] = cvt_pk_bf16(oacc[mi][di][0], oacc[mi][di][1]);
        pk[1] = cvt_pk_bf16(oacc[mi][di][2], oacc[mi][di][3]);
        *(uint2v*)&Ob[(mi*16 + l15)*HEAD + di*16 + lg*4] = pk;
      }
      if (lg == 0){
        float* mlb = pML + (size_t)pslot*64 + (mi*16 + l15)*2;
        mlb[0] = mrun[mi];
        mlb[1] = lrun[mi];
      }
    }
  }
}

// ---------------- combine partials ----------------
__global__ __launch_bounds__(256)
void attn_combine(const unsigned short* __restrict__ pO, const float* __restrict__ pML,
                  unsigned short* __restrict__ ctx)
{
  const int bid = blockIdx.x;              // 64*48
  const int bh = bid / 48, qcp = bid - (bid/48)*48;
  const int qc = 16 + qcp;
  int base, np;
  if (qcp < 16){ base = qcp*2; np = 2; }
  else if (qcp < 32){ base = 32 + (qcp-16)*3; np = 3; }
  else { base = 80 + (qcp-32)*4; np = 4; }
  const int slot0 = bh*PART_SLOTS + base;
  const int row = threadIdx.x >> 3;        // 0..31
  const int cg  = threadIdx.x & 7;         // 0..7
  const float SC = 0.1118033988749895f * 1.4426950408889634f;

  float m[4], l[4];
  float ms = -3e38f;
  for (int p=0;p<np;p++){
    m[p] = pML[(size_t)(slot0+p)*64 + row*2];
    l[p] = pML[(size_t)(slot0+p)*64 + row*2 + 1];
    ms = fmaxf(ms, m[p]);
  }
  float wgt[4], lsum = 0.0f;
  for (int p=0;p<np;p++){
    wgt[p] = exp2f((m[p]-ms)*SC);
    lsum += wgt[p]*l[p];
  }
  const float inv = 1.0f/lsum;
  const int b = bh >> 5, h = bh & 31;
  const size_t crow = ((size_t)(b*SEQ + qc*32 + row))*HIDDEN + h*HEAD;
  for (int d = cg*10; d < cg*10 + 10; d++){
    float acc = 0.0f;
    for (int p=0;p<np;p++)
      acc += wgt[p]*bf2f(pO[(size_t)(slot0+p)*32*HEAD + row*HEAD + d]);
    ctx[crow + d] = f2bf(acc*inv);
  }
}

// ---------------- launch ----------------
extern "C" void kernel_launch(void* const* d_in, const int* in_sizes, int n_in,
                              void* d_out, int out_size, void* d_ws, size_t ws_size,
                              hipStream_t stream)
{
  const int*   pos  = (const int*)  d_in[0];
  const float* hid  = (const float*)d_in[1];
  const float* wqkv = (const float*)d_in[2];
  const float* bqkv = (const float*)d_in[3];
  const float* outw = (const float*)d_in[4];
  const float* outb = (const float*)d_in[5];

  char* ws = (char*)d_ws;
  size_t off = 0;
  auto alloc = [&](size_t bytes)->void*{
    void* p = ws + off; off += (bytes + 255) & ~(size_t)255; return p;
  };
  unsigned short* hid_bf  = (unsigned short*)alloc((size_t)M_TOTAL*HIDDEN*2);   // reused as ctx
  unsigned short* wqkv_bf = (unsigned short*)alloc((size_t)QKV_N*HIDDEN*2);
  unsigned short* outw_bf = (unsigned short*)alloc((size_t)HIDDEN*HIDDEN*2);
  unsigned short* qkv_bf  = (unsigned short*)alloc((size_t)M_TOTAL*QKV_N*2);    // reused as partials
  unsigned short* Qp      = (unsigned short*)alloc((size_t)BATCH*NHEADS*SEQ*DSTRIDE*2);
  unsigned short* Kp      = (unsigned short*)alloc((size_t)BATCH*NHEADS*SEQ*DSTRIDE*2);
  unsigned short* Vt      = (unsigned short*)alloc((size_t)BATCH*NHEADS*HEAD*SEQ*2);
  if (off > ws_size) return;

  // partials alias qkv_bf (dead after rope_scatter): 9216 slots
  unsigned short* pO  = qkv_bf;                                   // 9216*32*80*2 = 47.2MB
  float*          pML = (float*)(qkv_bf + (size_t)64*PART_SLOTS*32*HEAD); // 9216*64*4 = 2.36MB

  convert_f32_bf16<<<dim3(1024), dim3(256), 0, stream>>>(hid,  hid_bf,  M_TOTAL*HIDDEN/4);
  convert_f32_bf16<<<dim3(2048), dim3(256), 0, stream>>>(wqkv, wqkv_bf, QKV_N*HIDDEN/4);
  convert_f32_bf16<<<dim3(1024), dim3(256), 0, stream>>>(outw, outw_bf, HIDDEN*HIDDEN/4);

  gemm_bt<true><<<dim3(QKV_N/128, M_TOTAL/128), dim3(256), 0, stream>>>(
      hid_bf, wqkv_bf, bqkv, (void*)qkv_bf, M_TOTAL, QKV_N, HIDDEN);

  rope_scatter<<<dim3(BATCH*NHEADS*16), dim3(256), 0, stream>>>(qkv_bf, pos, Qp, Kp, Vt);

  unsigned short* ctx = hid_bf;  // hidden_bf dead after QKV GEMM
  attn_fd<<<dim3(2560), dim3(256), 0, stream>>>(Qp, Kp, Vt, ctx, pO, pML);
  attn_combine<<<dim3(64*48), dim3(256), 0, stream>>>(pO, pML, ctx);

  gemm_bt<false><<<dim3(HIDDEN/128, M_TOTAL/128), dim3(256), 0, stream>>>(
      ctx, outw_bf, outb, d_out, M_TOTAL, HIDDEN, HIDDEN);
}